// Round 7
// baseline (37.882 us; speedup 1.0000x reference)
//
#include <hip/hip_runtime.h>

// LSP -> LPC, LPC_ORDER = 24, rows of 25 fp32: [K, ang0..ang23]
// Conjugate-pair roots => real quadratics (x^2 - 2cos th x + 1); product of
// palindromic quadratics is palindromic: keep coeffs 0..12; P,Q packed as
// float2 -> v_pk_fma_f32 (R5). Normal loads (L3-resident input) +
// non-temporal stores (R4: halved HBM fetch).
//
// R7: BARRIER-FREE wave-independent tiles. Each wave owns a private 6.4KB
// LDS chunk (64 rows); wave-lockstep SIMD + compiler lgkmcnt ordering make
// __syncthreads unnecessary -> no per-tile vmcnt(0)/lgkmcnt(0) full drain
// (the known ~20% convoy stall), waves free-run at different phases.

typedef float f4 __attribute__((ext_vector_type(4)));
typedef float f2 __attribute__((ext_vector_type(2)));

static constexpr int NC   = 25;
static constexpr int RPW  = 64;                       // rows per wave-tile
static constexpr int FPW  = NC * RPW;                 // 1600 floats per tile
static constexpr int V4W  = FPW / 4;                  // 400 f4 per tile
static constexpr int TAIL = V4W - 6 * 64;             // 16

__global__ __launch_bounds__(256)
void lsp2lpc_kernel(const float* __restrict__ in, float* __restrict__ out) {
    __shared__ float lds[4 * FPW];                    // 25.6 KB, 6.4KB/wave
    const int tid  = threadIdx.x;
    const int wid  = tid >> 6;
    const int lane = tid & 63;

    float* chunk = &lds[wid * FPW];                   // wave-private
    f4*    c4    = reinterpret_cast<f4*>(chunk);

    const int tile = blockIdx.x * 4 + wid;            // 4096 tiles total
    const size_t base = (size_t)tile * FPW;           // 6400 B aligned

    // coalesced f4 global -> wave-private LDS (normal loads: L3 input reuse)
    const f4* gin = reinterpret_cast<const f4*>(in + base);
#pragma unroll
    for (int i = 0; i < 6; ++i)
        c4[lane + i * 64] = gin[lane + i * 64];
    if (lane < TAIL)
        c4[lane + 6 * 64] = gin[lane + 6 * 64];
    // no __syncthreads: wave-lockstep + lgkmcnt orders LDS write->read

    // per-lane row (stride 25 = odd -> 2 lanes/bank, conflict-free)
    const float* row = &chunk[lane * NC];
    const float K = row[0];
    f2 tcoef[12];                                     // {tp, tq} per pair
#pragma unroll
    for (int m = 0; m < 12; ++m) {
        const float cq = __cosf(row[1 + 2 * m]);      // Q: ang idx 0,2,..,22
        const float cp = __cosf(row[2 + 2 * m]);      // P: ang idx 1,3,..,23
        tcoef[m] = (f2){-2.f * cp, -2.f * cq};
    }

    f2 PQ[13];                                        // {P[k], Q[k]}
#pragma unroll
    for (int k = 0; k < 13; ++k) PQ[k] = (f2){0.f, 0.f};
    PQ[0] = (f2){1.f, 1.f};

#pragma unroll
    for (int m = 0; m < 12; ++m) {
        const f2 tm = tcoef[m];
        const int kmax = (2 * m + 2 < 12) ? (2 * m + 2) : 12;
#pragma unroll
        for (int k = 12; k >= 0; --k) {
            if (k > kmax) continue;                   // compile-time pruned
            const f2 c1 = (k >= 1) ? PQ[k - 1] : (f2){0.f, 0.f};
            const f2 c2 = (k >= 2) ? PQ[k - 2] : (f2){0.f, 0.f};
            PQ[k] = __builtin_elementwise_fma(tm, c1, PQ[k]) + c2;
        }
    }

    // epilogue: a[k] = 0.5*(u[i1] + v[i0]); u = P+Q, v = Q-P, palindromic
    float u[13], v[13];
#pragma unroll
    for (int k = 0; k < 13; ++k) {
        u[k] = PQ[k].x + PQ[k].y;
        v[k] = PQ[k].y - PQ[k].x;
    }
    float* orow = &chunk[lane * NC];
    orow[0] = K;
#pragma unroll
    for (int k = 0; k < 24; ++k) {
        const int i0 = (k     <= 12) ? k       : 24 - k;
        const int i1 = (k + 1 <= 12) ? (k + 1) : 24 - (k + 1);
        orow[1 + k] = 0.5f * (u[i1] + v[i0]);
    }
    // no __syncthreads: same-wave lanes wrote, same-wave lanes read below

    // coalesced f4 LDS -> global, NON-TEMPORAL (keep input in L3)
    f4* gout = reinterpret_cast<f4*>(out + base);
#pragma unroll
    for (int i = 0; i < 6; ++i)
        __builtin_nontemporal_store(c4[lane + i * 64], &gout[lane + i * 64]);
    if (lane < TAIL)
        __builtin_nontemporal_store(c4[lane + 6 * 64], &gout[lane + 6 * 64]);
}

extern "C" void kernel_launch(void* const* d_in, const int* in_sizes, int n_in,
                              void* d_out, int out_size, void* d_ws, size_t ws_size,
                              hipStream_t stream) {
    const float* in  = (const float*)d_in[0];
    float*       out = (float*)d_out;
    const int nrows   = in_sizes[0] / NC;             // 1048576
    const int ntiles  = nrows / RPW;                  // 16384
    const int nblocks = ntiles / 4;                   // 4096 (exact)
    lsp2lpc_kernel<<<nblocks, 256, 0, stream>>>(in, out);
}

// Round 8
// 37.453 us; speedup vs baseline: 1.0115x; 1.0115x over previous
//
#include <hip/hip_runtime.h>

// LSP -> LPC, LPC_ORDER = 24, rows of 25 fp32: [K, ang0..ang23]
// Conjugate-pair roots => real quadratics (x^2 - 2cos th x + 1); product of
// palindromic quadratics is palindromic: keep coeffs 0..12 only.
//
// R8: lane-PAIR row split for 100% occupancy. Even lane builds Q's half
// (angles 1,3,..,23), odd lane builds P's half (angles 2,4,..,24) of the
// SAME row; combine via v_mov_b32_dpp quad_perm swap (VALU, no DS).
// LDS = 50 B/thread -> 12.8 KB/block -> 8 blocks/CU = 2048 thr (100% occ,
// vs 24-wave cap at 100 B/thread in R1-R7). Memory path unchanged:
// normal loads (L3-resident input) + non-temporal stores (R4).

typedef float f4 __attribute__((ext_vector_type(4)));

static constexpr int NC   = 25;
static constexpr int RPW  = 32;                      // rows per wave-tile
static constexpr int FPW  = NC * RPW;                // 800 floats per tile
static constexpr int V4W  = FPW / 4;                 // 200 f4 per tile

__device__ __forceinline__ float xor1(float x) {
    // swap lanes 0<->1, 2<->3 within each quad: dpp_ctrl quad_perm[1,0,3,2]
    int i = __float_as_int(x);
    i = __builtin_amdgcn_mov_dpp(i, 0xB1, 0xF, 0xF, true);
    return __int_as_float(i);
}

__global__ __launch_bounds__(256, 8)
void lsp2lpc_kernel(const float* __restrict__ in, float* __restrict__ out) {
    __shared__ float lds[4 * FPW];                   // 12.8 KB
    const int tid  = threadIdx.x;
    const int wid  = tid >> 6;
    const int lane = tid & 63;

    float* chunk = &lds[wid * FPW];                  // wave-private 3.2 KB
    f4*    c4    = reinterpret_cast<f4*>(chunk);

    const int tile = blockIdx.x * 4 + wid;           // 32768 tiles total
    const size_t base = (size_t)tile * FPW;          // 3200 B -> 16B aligned

    // coalesced f4 global -> wave-private LDS (normal loads: L3 reuse)
    const f4* gin = reinterpret_cast<const f4*>(in + base);
#pragma unroll
    for (int i = 0; i < 3; ++i)
        c4[lane + i * 64] = gin[lane + i * 64];
    if (lane < V4W - 192)                            // 8 tail f4
        c4[lane + 192] = gin[lane + 192];
    // no barrier: wave-lockstep + lgkmcnt orders LDS write->read

    const int lrow = lane >> 1;                      // 32 rows per wave
    const int p    = lane & 1;                       // 0 => Q half, 1 => P half
    const float* row = &chunk[lrow * NC];
    const float K = row[0];                          // broadcast pairs, free

    // own 12 angles: Q uses idx 1+2m, P uses idx 2+2m (bijective mod 32 per
    // parity class -> 2 lanes/bank, conflict-free)
    float t[12];
#pragma unroll
    for (int m = 0; m < 12; ++m)
        t[m] = -2.f * __cosf(row[1 + p + 2 * m]);

    // palindromic lower half, scalar recurrence (c[0]=1 fixed)
    float c[13];
    c[0] = 1.f;
#pragma unroll
    for (int k = 1; k < 13; ++k) c[k] = 0.f;
#pragma unroll
    for (int m = 0; m < 12; ++m) {
        const float tm = t[m];
        const int kmax = (2 * m + 2 < 12) ? (2 * m + 2) : 12;
#pragma unroll
        for (int k = 12; k >= 1; --k) {
            if (k > kmax) continue;                  // compile-time pruned
            const float c1 = c[k - 1];
            const float c2 = (k >= 2) ? c[k - 2] : 0.f;
            c[k] = fmaf(tm, c1, c[k]) + c2;
        }
    }

    // pair exchange (VALU dpp): u = 0.5(P+Q), d = 0.5(own - partner)
    // even lane: d = 0.5(Q-P) = +0.5 v ; odd lane: d = 0.5(P-Q) = -0.5 v
    float u[13], d[13];
#pragma unroll
    for (int k = 0; k < 13; ++k) {
        const float pc = xor1(c[k]);
        u[k] = 0.5f * (c[k] + pc);
        d[k] = 0.5f * (c[k] - pc);
    }

    // a[k] = 0.5*(u_f[k+1] + v_f[k]) with palindromic fold of indices;
    // even lane writes out positions 0..12 (K, a0..a11), odd 13..24 (a12..a23)
    float* orow = &chunk[lrow * NC];
    if (p == 0) {
        orow[0] = K;
#pragma unroll
        for (int k = 0; k < 12; ++k)                 // i0=k, i1=k+1 (<=12)
            orow[1 + k] = u[k + 1] + d[k];
    } else {
#pragma unroll
        for (int k = 12; k < 24; ++k) {              // i0 = 24-k (k>12), i1 = 23-k
            const int i0 = (k <= 12) ? k : 24 - k;
            const int i1 = 23 - k + 0;               // 24-(k+1), k+1>=13
            orow[1 + k] = u[i1] - d[i0];
        }
    }
    // no barrier: same-wave write->read

    // coalesced f4 LDS -> global, NON-TEMPORAL (keep input in L3)
    f4* gout = reinterpret_cast<f4*>(out + base);
#pragma unroll
    for (int i = 0; i < 3; ++i)
        __builtin_nontemporal_store(c4[lane + i * 64], &gout[lane + i * 64]);
    if (lane < V4W - 192)
        __builtin_nontemporal_store(c4[lane + 192], &gout[lane + 192]);
}

extern "C" void kernel_launch(void* const* d_in, const int* in_sizes, int n_in,
                              void* d_out, int out_size, void* d_ws, size_t ws_size,
                              hipStream_t stream) {
    const float* in  = (const float*)d_in[0];
    float*       out = (float*)d_out;
    const int nrows   = in_sizes[0] / NC;            // 1048576
    const int ntiles  = nrows / RPW;                 // 32768
    const int nblocks = ntiles / 4;                  // 8192 (exact)
    lsp2lpc_kernel<<<nblocks, 256, 0, stream>>>(in, out);
}